// Round 2
// baseline (1260.472 us; speedup 1.0000x reference)
//
#include <hip/hip_runtime.h>
#include <math.h>

#define X_DIM   50
#define SEQ_LEN 230
#define BATCH   16384
#define KTRUE   150      // 3 * X_DIM
#define NOUT    1380     // Y_DIM * SEQ_LEN
#define BM      8        // batches per block
#define FSTR    156      // LDS flat row stride (floats): 156%32=28 -> 8 rows hit 8
                         // distinct banks; 156*4%16==0 -> float4-aligned rows
#define NCOLS   6        // output cols per thread: n = tid + 256*j

typedef float v2f __attribute__((ext_vector_type(2)));

__device__ __forceinline__ v2f vmax2(v2f a, v2f b) {
    v2f r; r.x = fmaxf(a.x, b.x); r.y = fmaxf(a.y, b.y); return r;
}

// ---------------------------------------------------------------------------
// Fully fused: depthwise conv (k=3,6,12) + max  ->  LDS  ->  8x1380 GEMM.
// One block = 8 batches. No global intermediate, workspace unused.
// ---------------------------------------------------------------------------
__global__ __launch_bounds__(256) void fused_cnn(
    const float* __restrict__ x,   // [B, 230, 50]
    const float* __restrict__ w1, const float* __restrict__ b1,
    const float* __restrict__ w2, const float* __restrict__ b2,
    const float* __restrict__ w3, const float* __restrict__ b3,
    const float* __restrict__ wo,  // [1380, 150]
    const float* __restrict__ bo,  // [1380]
    float* __restrict__ out)       // [B, 1380]
{
    __shared__ float flatS[BM * FSTR];

    const int tid = threadIdx.x;
    const int b0  = blockIdx.x * BM;

    // ------------- phase 1: conv + max, threads 0..199 (8 batches x 25 pairs)
    if (tid < BM * 25) {
        const int lb = tid / 25;
        const int cp = tid - lb * 25;
        const int c0 = 2 * cp, c1 = c0 + 1;

        const v2f* p = reinterpret_cast<const v2f*>(
            x + (size_t)(b0 + lb) * (SEQ_LEN * X_DIM)) + cp;

        v2f W1c[3], W2c[6], W3c[12];
#pragma unroll
        for (int i = 0; i < 3; ++i)  { W1c[i].x = w1[c0*3+i];  W1c[i].y = w1[c1*3+i]; }
#pragma unroll
        for (int i = 0; i < 6; ++i)  { W2c[i].x = w2[c0*6+i];  W2c[i].y = w2[c1*6+i]; }
#pragma unroll
        for (int i = 0; i < 12; ++i) { W3c[i].x = w3[c0*12+i]; W3c[i].y = w3[c1*12+i]; }

        v2f m1 = {-1e30f, -1e30f}, m2 = m1, m3 = m1;
        v2f buf[12];

        // prologue t = 0..11
#pragma unroll
        for (int t = 0; t < 12; ++t) {
            v2f v = p[t * 25];
            buf[t] = v;
            if (t >= 2) {
                v2f s = buf[t-2] * W1c[0] + buf[t-1] * W1c[1] + v * W1c[2];
                m1 = vmax2(m1, s);
            }
            if (t >= 5) {
                v2f s = buf[t-5] * W2c[0];
#pragma unroll
                for (int i = 1; i < 6; ++i) s += buf[t-5+i] * W2c[i];
                m2 = vmax2(m2, s);
            }
            if (t == 11) {
                v2f s = buf[0] * W3c[0];
#pragma unroll
                for (int i = 1; i < 12; ++i) s += buf[i] * W3c[i];
                m3 = vmax2(m3, s);
            }
        }

        // main t = 12..227, 18 chunks of 12 (static ring indices)
        const v2f* q = p + 12 * 25;
#pragma unroll 2
        for (int it = 0; it < 18; ++it) {
#pragma unroll
            for (int j = 0; j < 12; ++j) {
                v2f v = q[j * 25];
                buf[j] = v;
                v2f s1 = buf[(j+10)%12] * W1c[0] + buf[(j+11)%12] * W1c[1] + v * W1c[2];
                m1 = vmax2(m1, s1);
                v2f s2 = buf[(j+7)%12] * W2c[0];
#pragma unroll
                for (int i = 1; i < 6; ++i) s2 += buf[(j+7+i)%12] * W2c[i];
                m2 = vmax2(m2, s2);
                v2f s3 = buf[(j+1)%12] * W3c[0];
#pragma unroll
                for (int i = 1; i < 12; ++i) s3 += buf[(j+1+i)%12] * W3c[i];
                m3 = vmax2(m3, s3);
            }
            q += 12 * 25;
        }

        // epilogue t = 228, 229
#pragma unroll
        for (int j = 0; j < 2; ++j) {
            v2f v = q[j * 25];
            buf[j] = v;
            v2f s1 = buf[(j+10)%12] * W1c[0] + buf[(j+11)%12] * W1c[1] + v * W1c[2];
            m1 = vmax2(m1, s1);
            v2f s2 = buf[(j+7)%12] * W2c[0];
#pragma unroll
            for (int i = 1; i < 6; ++i) s2 += buf[(j+7+i)%12] * W2c[i];
            m2 = vmax2(m2, s2);
            v2f s3 = buf[(j+1)%12] * W3c[0];
#pragma unroll
            for (int i = 1; i < 12; ++i) s3 += buf[(j+1+i)%12] * W3c[i];
            m3 = vmax2(m3, s3);
        }

        // bias is position-invariant: max(conv+b) = max(conv)+b
        float* f = flatS + lb * FSTR + 6 * cp;
        f[0] = m1.x + b1[c0];
        f[1] = m2.x + b2[c0];
        f[2] = m3.x + b3[c0];
        f[3] = m1.y + b1[c1];
        f[4] = m2.y + b2[c1];
        f[5] = m3.y + b3[c1];
    }
    __syncthreads();

    // ------------- phase 2: out[8][1380] = flat[8][150] @ wo^T + bo ---------
    // Thread owns all 8 rows x 6 cols (n = tid + 256*j). A-reads are
    // same-address LDS broadcasts (free); w-reads grouped in 8-k bursts for
    // L1 line locality; w_out (828 KB) is L2/L3-resident.
    const float* wp_[NCOLS];
#pragma unroll
    for (int j = 0; j < NCOLS; ++j) {
        int n = tid + 256 * j;
        if (n > NOUT - 1) n = NOUT - 1;     // clamp: loads stay in-bounds
        wp_[j] = wo + (size_t)n * KTRUE;
    }

    float acc[NCOLS][BM];
#pragma unroll
    for (int j = 0; j < NCOLS; ++j)
#pragma unroll
        for (int r = 0; r < BM; ++r) acc[j][r] = 0.f;

    // main: 18 chunks of 8 k  (k = 0..143)
#pragma unroll 1
    for (int kb = 0; kb < 18; ++kb) {
        const int k0 = kb * 8;
        v2f wreg[NCOLS][4];
#pragma unroll
        for (int j = 0; j < NCOLS; ++j)
#pragma unroll
            for (int qq = 0; qq < 4; ++qq)
                wreg[j][qq] = *reinterpret_cast<const v2f*>(wp_[j] + k0 + 2*qq);

#pragma unroll
        for (int r = 0; r < BM; ++r) {
            float4 aa = *reinterpret_cast<const float4*>(&flatS[r*FSTR + k0]);
            float4 ab = *reinterpret_cast<const float4*>(&flatS[r*FSTR + k0 + 4]);
            float av[8] = {aa.x, aa.y, aa.z, aa.w, ab.x, ab.y, ab.z, ab.w};
#pragma unroll
            for (int j = 0; j < NCOLS; ++j) {
#pragma unroll
                for (int qq = 0; qq < 4; ++qq) {
                    acc[j][r] = fmaf(av[2*qq+0], wreg[j][qq].x, acc[j][r]);
                    acc[j][r] = fmaf(av[2*qq+1], wreg[j][qq].y, acc[j][r]);
                }
            }
        }
    }

    // tail: k = 144..149
    {
        const int k0 = 144;
        v2f wreg[NCOLS][3];
#pragma unroll
        for (int j = 0; j < NCOLS; ++j)
#pragma unroll
            for (int qq = 0; qq < 3; ++qq)
                wreg[j][qq] = *reinterpret_cast<const v2f*>(wp_[j] + k0 + 2*qq);

#pragma unroll
        for (int r = 0; r < BM; ++r) {
            float4 aa = *reinterpret_cast<const float4*>(&flatS[r*FSTR + k0]);
            v2f    ab = *reinterpret_cast<const v2f*>(&flatS[r*FSTR + k0 + 4]);
            float av[6] = {aa.x, aa.y, aa.z, aa.w, ab.x, ab.y};
#pragma unroll
            for (int j = 0; j < NCOLS; ++j) {
#pragma unroll
                for (int qq = 0; qq < 3; ++qq) {
                    acc[j][r] = fmaf(av[2*qq+0], wreg[j][qq].x, acc[j][r]);
                    acc[j][r] = fmaf(av[2*qq+1], wreg[j][qq].y, acc[j][r]);
                }
            }
        }
    }

    // store: coalesced 4B/lane (lanes -> consecutive n)
#pragma unroll
    for (int j = 0; j < NCOLS; ++j) {
        int n = tid + 256 * j;
        if (n < NOUT) {
            float bb = bo[n];
#pragma unroll
            for (int r = 0; r < BM; ++r)
                out[(size_t)(b0 + r) * NOUT + n] = acc[j][r] + bb;
        }
    }
}

// ---------------------------------------------------------------------------
extern "C" void kernel_launch(void* const* d_in, const int* in_sizes, int n_in,
                              void* d_out, int out_size, void* d_ws, size_t ws_size,
                              hipStream_t stream) {
    const float* seq   = (const float*)d_in[0];
    const float* w1    = (const float*)d_in[1];
    const float* b1    = (const float*)d_in[2];
    const float* w2    = (const float*)d_in[3];
    const float* b2    = (const float*)d_in[4];
    const float* w3    = (const float*)d_in[5];
    const float* b3    = (const float*)d_in[6];
    const float* w_out = (const float*)d_in[7];
    const float* b_out = (const float*)d_in[8];
    float* out = (float*)d_out;

    (void)d_ws; (void)ws_size;   // workspace intentionally unused

    fused_cnn<<<BATCH / BM, 256, 0, stream>>>(
        seq, w1, b1, w2, b2, w3, b3, w_out, b_out, out);
}